// Round 2
// 9958.548 us; speedup vs baseline: 2.9767x; 2.9767x over previous
//
#include <hip/hip_runtime.h>
#include <cstdint>
#include <cstddef>

// Problem dims (fixed by reference)
#define B_   128
#define T_   128
#define V_   10000
#define E_   256
#define H_   1024
#define D_   128
#define G3_  3072  // 3*H
#define GRID_ 256  // gru_all grid = 1 block/CU (LDS-forced co-residency)

__device__ __forceinline__ float sigmoid_(float x) {
  return 1.0f / (1.0f + __expf(-x));
}

// ---------------------------------------------------------------------------
// Graph-capture-safe barrier reset (runs before gru_all each replay).
// ---------------------------------------------------------------------------
__global__ void bar_reset(unsigned int* bar) { *bar = 0u; }

// ---------------------------------------------------------------------------
// Persistent GRU: ONE plain kernel runs all T=128 steps with a manual
// device-scope grid barrier (no cooperative launch -> graph-capture safe).
// Grid: 256 blocks x 256 threads; 130 KB static LDS forces 1 block/CU, so
// all 256 blocks are co-resident on the 256 CUs (persistent-kernel premise).
// LDS:
//   wT[3][4][1024]  rk slice, transposed [gate][j][k]  (48 KB, loaded once)
//   gT[3][4][256]   gk slice, transposed               (12 KB, loaded once)
//   tok16[128][128] all tokens as u16 (V<65536)        (32 KB, loaded once)
//   a_lds[128][72]  activation tile; pad 72: 4-way banks, 16B-aligned rows
//   hn_lds[128][4]  output transpose staging
// Thread owns (b_lo, b_lo+64) x (one j) x 3 gates; h_prev carried in regs.
// Barrier is split arrive/wait: arrive right after storing h[t]; wait just
// before the recurrent matmul of t+1, so the independent emb-side matmul of
// t+1 overlaps stragglers and barrier latency.
// ---------------------------------------------------------------------------
__global__ __launch_bounds__(256, 1) void gru_all(
    const int* __restrict__ tokens, const float* __restrict__ emb,
    const float* __restrict__ gk, const float* __restrict__ rk,
    const float* __restrict__ bi, const float* __restrict__ br,
    float* __restrict__ hs, unsigned int* __restrict__ bar) {
  __shared__ float wT[3][4][H_];            // 49152 B
  __shared__ float gT[3][4][E_];            // 12288 B
  __shared__ unsigned short tok16[128][T_]; // 32768 B
  __shared__ float a_lds[128][72];          // 36864 B
  __shared__ float hn_lds[128][4];          //  2048 B

  const int tid = threadIdx.x;
  const int b_lo = tid & 63;
  const int j_idx = tid >> 6;        // 0..3, wave-uniform
  const int j0 = blockIdx.x << 2;
  const int j = j0 + j_idx;
  const int lk = tid & 63;           // k lane for tile loads
  const int lb0 = tid >> 6;          // base b for tile loads

  // ---- one-time preload: weights (transposed) + tokens ----
  for (int i = tid; i < H_ * 3; i += 256) {
    int k = i / 3, g = i - 3 * k;
    float4 v = *(const float4*)&rk[(size_t)k * G3_ + (g << 10) + j0];
    wT[g][0][k] = v.x; wT[g][1][k] = v.y; wT[g][2][k] = v.z; wT[g][3][k] = v.w;
  }
  for (int i = tid; i < E_ * 3; i += 256) {
    int k = i / 3, g = i - 3 * k;
    float4 v = *(const float4*)&gk[(size_t)k * G3_ + (g << 10) + j0];
    gT[g][0][k] = v.x; gT[g][1][k] = v.y; gT[g][2][k] = v.z; gT[g][3][k] = v.w;
  }
  for (int i = tid; i < B_ * T_; i += 256)
    tok16[i >> 7][i & (T_ - 1)] = (unsigned short)tokens[i];

  const float bi_z = bi[j], bi_r = bi[H_ + j], bi_h = bi[2 * H_ + j];
  const float br_z = br[j], br_r = br[H_ + j], br_h = br[2 * H_ + j];

  float hp0 = 0.f, hp1 = 0.f;  // h[t-1] at this thread's (b,j), in registers

  for (int t = 0; t < T_; ++t) {
    float xz0 = 0.f, xr0 = 0.f, xh0 = 0.f, xz1 = 0.f, xr1 = 0.f, xh1 = 0.f;
    float hz0 = 0.f, hr0 = 0.f, hh0 = 0.f, hz1 = 0.f, hh1 = 0.f, hr1 = 0.f;

    // ---- input side first (no dependence on h[t-1]): overlaps the barrier
    for (int ec = 0; ec < E_; ec += 64) {
      __syncthreads();
      #pragma unroll
      for (int i = 0; i < 32; ++i) {
        int b = lb0 + (i << 2);
        a_lds[b][lk] = emb[(size_t)tok16[b][t] * E_ + ec + lk];
      }
      __syncthreads();
      for (int k = 0; k < 64; k += 4) {
        float a0v[4], a1v[4], wz[4], wr[4], wh[4];
        *(float4*)a0v = *(const float4*)&a_lds[b_lo][k];
        *(float4*)a1v = *(const float4*)&a_lds[b_lo + 64][k];
        *(float4*)wz = *(const float4*)&gT[0][j_idx][ec + k];
        *(float4*)wr = *(const float4*)&gT[1][j_idx][ec + k];
        *(float4*)wh = *(const float4*)&gT[2][j_idx][ec + k];
        #pragma unroll
        for (int u = 0; u < 4; ++u) {
          xz0 = fmaf(a0v[u], wz[u], xz0);
          xr0 = fmaf(a0v[u], wr[u], xr0);
          xh0 = fmaf(a0v[u], wh[u], xh0);
          xz1 = fmaf(a1v[u], wz[u], xz1);
          xr1 = fmaf(a1v[u], wr[u], xr1);
          xh1 = fmaf(a1v[u], wh[u], xh1);
        }
      }
    }

    // ---- wait: h[t-1] fully published by all blocks ----
    if (t > 0) {
      if (tid == 0) {
        const unsigned int tgt = (unsigned)GRID_ * (unsigned)t;
        while (__hip_atomic_load(bar, __ATOMIC_RELAXED,
                                 __HIP_MEMORY_SCOPE_AGENT) < tgt)
          __builtin_amdgcn_s_sleep(2);
        __threadfence();  // acquire: invalidate stale L1/L2 lines
      }
      __syncthreads();

      // ---- recurrent side: rg = h[t-1] @ rk  (K = 1024) ----
      const float* __restrict__ hprev = hs + (size_t)(t - 1) * (B_ * H_);
      for (int kc = 0; kc < H_; kc += 64) {
        __syncthreads();
        #pragma unroll
        for (int i = 0; i < 32; ++i) {
          int b = lb0 + (i << 2);
          a_lds[b][lk] = hprev[(size_t)b * H_ + kc + lk];
        }
        __syncthreads();
        for (int k = 0; k < 64; k += 4) {
          float a0v[4], a1v[4], wz[4], wr[4], wh[4];
          *(float4*)a0v = *(const float4*)&a_lds[b_lo][k];
          *(float4*)a1v = *(const float4*)&a_lds[b_lo + 64][k];
          *(float4*)wz = *(const float4*)&wT[0][j_idx][kc + k];
          *(float4*)wr = *(const float4*)&wT[1][j_idx][kc + k];
          *(float4*)wh = *(const float4*)&wT[2][j_idx][kc + k];
          #pragma unroll
          for (int u = 0; u < 4; ++u) {
            hz0 = fmaf(a0v[u], wz[u], hz0);
            hr0 = fmaf(a0v[u], wr[u], hr0);
            hh0 = fmaf(a0v[u], wh[u], hh0);
            hz1 = fmaf(a1v[u], wz[u], hz1);
            hr1 = fmaf(a1v[u], wr[u], hr1);
            hh1 = fmaf(a1v[u], wh[u], hh1);
          }
        }
      }
    }

    // ---- gate epilogue (identical math to reference) ----
    float z0 = sigmoid_(xz0 + bi_z + hz0 + br_z);
    float r0 = sigmoid_(xr0 + bi_r + hr0 + br_r);
    float c0 = tanhf(xh0 + bi_h + r0 * (hh0 + br_h));
    float hn0 = z0 * hp0 + (1.f - z0) * c0;

    float z1 = sigmoid_(xz1 + bi_z + hz1 + br_z);
    float r1 = sigmoid_(xr1 + bi_r + hr1 + br_r);
    float c1 = tanhf(xh1 + bi_h + r1 * (hh1 + br_h));
    float hn1 = z1 * hp1 + (1.f - z1) * c1;

    hp0 = hn0; hp1 = hn1;

    hn_lds[b_lo][j_idx] = hn0;
    hn_lds[b_lo + 64][j_idx] = hn1;
    __syncthreads();
    if (tid < 128) {
      float4 v = *(const float4*)&hn_lds[tid][0];
      *(float4*)&hs[((size_t)t * B_ + tid) * H_ + j0] = v;
    }
    __syncthreads();  // drains all waves' vmcnt -> stores are in L2

    // ---- arrive: publish h[t] (wait happens next iteration, after emb side)
    if (t + 1 < T_ && tid == 0) {
      __threadfence();  // release: writeback L2 so other XCDs can see h[t]
      __hip_atomic_fetch_add(bar, 1u, __ATOMIC_RELEASE,
                             __HIP_MEMORY_SCOPE_AGENT);
    }
  }
}

// ---------------------------------------------------------------------------
// d = relu(hs @ w1 + b1): [16384,1024]x[1024,128]. 64-row tiles, 4x8/thread.
// ---------------------------------------------------------------------------
__global__ __launch_bounds__(256) void mlp1_kernel(
    const float* __restrict__ hs, const float* __restrict__ w1,
    const float* __restrict__ b1, float* __restrict__ dbuf) {
  __shared__ float A[64][68];
  __shared__ float Bs[64][128];
  const int tid = threadIdx.x;
  const int row0 = blockIdx.x * 64;
  const int tc = tid & 15;   // col group (8 cols)
  const int tr = tid >> 4;   // row group (4 rows)

  float acc[4][8];
  #pragma unroll
  for (int i = 0; i < 4; ++i)
    #pragma unroll
    for (int u = 0; u < 8; ++u) acc[i][u] = 0.f;

  const int lk = tid & 63, lr0 = tid >> 6;
  const int lc = tid & 127, lk0 = tid >> 7;

  for (int kc = 0; kc < H_; kc += 64) {
    __syncthreads();
    #pragma unroll
    for (int i = 0; i < 16; ++i) {
      int r = lr0 + (i << 2);
      A[r][lk] = hs[(size_t)(row0 + r) * H_ + kc + lk];
    }
    #pragma unroll
    for (int i = 0; i < 32; ++i) {
      int k = lk0 + (i << 1);
      Bs[k][lc] = w1[(size_t)(kc + k) * D_ + lc];
    }
    __syncthreads();
    for (int k = 0; k < 64; ++k) {
      float av[4];
      #pragma unroll
      for (int i = 0; i < 4; ++i) av[i] = A[(tr << 2) + i][k];
      float bv[8];
      *(float4*)&bv[0] = *(const float4*)&Bs[k][tc * 8];
      *(float4*)&bv[4] = *(const float4*)&Bs[k][tc * 8 + 4];
      #pragma unroll
      for (int i = 0; i < 4; ++i)
        #pragma unroll
        for (int u = 0; u < 8; ++u) acc[i][u] = fmaf(av[i], bv[u], acc[i][u]);
    }
  }

  float bb[8];
  #pragma unroll
  for (int u = 0; u < 8; ++u) bb[u] = b1[tc * 8 + u];
  #pragma unroll
  for (int i = 0; i < 4; ++i) {
    int row = row0 + (tr << 2) + i;
    float o[8];
    #pragma unroll
    for (int u = 0; u < 8; ++u) o[u] = fmaxf(acc[i][u] + bb[u], 0.f);
    *(float4*)&dbuf[(size_t)row * D_ + tc * 8] = *(float4*)&o[0];
    *(float4*)&dbuf[(size_t)row * D_ + tc * 8 + 4] = *(float4*)&o[4];
  }
}

// ---------------------------------------------------------------------------
// logits = d @ w2 + b2 -> written (unnormalized) into out at [b][t][v].
// rows are t-major (row = t*B + b); out index = (b*T + t)*V + v.
// ---------------------------------------------------------------------------
__global__ __launch_bounds__(256) void mlp2_logits(
    const float* __restrict__ dbuf, const float* __restrict__ w2,
    const float* __restrict__ b2, float* __restrict__ out) {
  __shared__ float A[64][68];
  __shared__ float Bs[64][128];
  const int tid = threadIdx.x;
  const int col0 = blockIdx.x * 128;
  const int row0 = blockIdx.y * 64;
  const int tc = tid & 15;
  const int tr = tid >> 4;

  float acc[4][8];
  #pragma unroll
  for (int i = 0; i < 4; ++i)
    #pragma unroll
    for (int u = 0; u < 8; ++u) acc[i][u] = 0.f;

  const int lk = tid & 63, lr0 = tid >> 6;
  const int lc = tid & 127, lk0 = tid >> 7;

  for (int kc = 0; kc < D_; kc += 64) {
    __syncthreads();
    #pragma unroll
    for (int i = 0; i < 16; ++i) {
      int r = lr0 + (i << 2);
      A[r][lk] = dbuf[(size_t)(row0 + r) * D_ + kc + lk];
    }
    #pragma unroll
    for (int i = 0; i < 32; ++i) {
      int k = lk0 + (i << 1);
      int col = col0 + lc;
      Bs[k][lc] = (col < V_) ? w2[(size_t)(kc + k) * V_ + col] : 0.f;
    }
    __syncthreads();
    for (int k = 0; k < 64; ++k) {
      float av[4];
      #pragma unroll
      for (int i = 0; i < 4; ++i) av[i] = A[(tr << 2) + i][k];
      float bv[8];
      *(float4*)&bv[0] = *(const float4*)&Bs[k][tc * 8];
      *(float4*)&bv[4] = *(const float4*)&Bs[k][tc * 8 + 4];
      #pragma unroll
      for (int i = 0; i < 4; ++i)
        #pragma unroll
        for (int u = 0; u < 8; ++u) acc[i][u] = fmaf(av[i], bv[u], acc[i][u]);
    }
  }

  const int colg = col0 + tc * 8;
  if (colg < V_) {  // V % 8 == 0, so a live float4x2 group is fully in-bounds
    float bb[8];
    #pragma unroll
    for (int u = 0; u < 8; ++u) bb[u] = b2[colg + u];
    #pragma unroll
    for (int i = 0; i < 4; ++i) {
      int row = row0 + (tr << 2) + i;
      int b = row & (B_ - 1);
      int tt = row >> 7;
      size_t base = ((size_t)b * T_ + tt) * V_ + colg;
      float o[8];
      #pragma unroll
      for (int u = 0; u < 8; ++u) o[u] = acc[i][u] + bb[u];
      *(float4*)&out[base] = *(float4*)&o[0];
      *(float4*)&out[base + 4] = *(float4*)&o[4];
    }
  }
}

// ---------------------------------------------------------------------------
// In-place temperature softmax over each V-row of out. One block per row.
// ---------------------------------------------------------------------------
__global__ __launch_bounds__(256) void softmax_rows(float* __restrict__ out) {
  __shared__ float buf[V_];
  __shared__ float red[8];
  const int tid = threadIdx.x;
  const size_t base = (size_t)blockIdx.x * V_;

  float m = -1e30f;
  for (int i = tid; i < V_; i += 256) {
    float v = out[base + i];
    buf[i] = v;
    m = fmaxf(m, v);
  }
  #pragma unroll
  for (int o = 32; o > 0; o >>= 1) m = fmaxf(m, __shfl_down(m, o));
  if ((tid & 63) == 0) red[tid >> 6] = m;
  __syncthreads();
  if (tid == 0) red[4] = fmaxf(fmaxf(red[0], red[1]), fmaxf(red[2], red[3]));
  __syncthreads();
  const float mall = red[4];

  float s = 0.f;
  for (int i = tid; i < V_; i += 256) {
    float e = __expf((buf[i] - mall) * 50.0f);  // /TEMP, TEMP=0.02
    buf[i] = e;
    s += e;
  }
  #pragma unroll
  for (int o = 32; o > 0; o >>= 1) s += __shfl_down(s, o);
  if ((tid & 63) == 0) red[tid >> 6] = s;
  __syncthreads();
  if (tid == 0) red[5] = red[0] + red[1] + red[2] + red[3];
  __syncthreads();
  const float inv = 1.0f / red[5];

  for (int i = tid; i < V_; i += 256) out[base + i] = buf[i] * inv;
}

// ---------------------------------------------------------------------------
extern "C" void kernel_launch(void* const* d_in, const int* in_sizes, int n_in,
                              void* d_out, int out_size, void* d_ws, size_t ws_size,
                              hipStream_t stream) {
  const int*   tokens = (const int*)d_in[0];
  const float* emb    = (const float*)d_in[1];
  const float* gru_k  = (const float*)d_in[2];
  const float* gru_rk = (const float*)d_in[3];
  const float* gru_bi = (const float*)d_in[4];
  const float* gru_br = (const float*)d_in[5];
  const float* w1     = (const float*)d_in[6];
  const float* b1     = (const float*)d_in[7];
  const float* w2     = (const float*)d_in[8];
  const float* b2     = (const float*)d_in[9];
  float* out = (float*)d_out;

  // workspace layout (floats): hs [T*B*H] then d [T*B*D]  => 75.5 MB total
  float* ws  = (float*)d_ws;
  float* hs  = ws;                         // 16,777,216 floats
  float* dbf = hs + (size_t)T_ * B_ * H_;  //  2,097,152 floats
  // barrier counter lives at dbf[0] during gru_all (dbf is written only
  // afterwards by mlp1, so no conflict); reset each replay by bar_reset.
  unsigned int* bar = (unsigned int*)dbf;

  bar_reset<<<1, 1, 0, stream>>>(bar);
  gru_all<<<GRID_, 256, 0, stream>>>(tokens, emb, gru_k, gru_rk,
                                     gru_bi, gru_br, hs, bar);
  mlp1_kernel<<<256, 256, 0, stream>>>(hs, w1, b1, dbf);
  mlp2_logits<<<dim3((V_ + 127) / 128, (T_ * B_) / 64), 256, 0, stream>>>(
      dbf, w2, b2, out);
  softmax_rows<<<T_ * B_, 256, 0, stream>>>(out);
}